// Round 1
// baseline (1486.119 us; speedup 1.0000x reference)
//
#include <hip/hip_runtime.h>
#include <cstddef>
#include <cstdint>

// Problem constants
#define B_   64
#define L_   256
#define E_   128
#define H_   2048
#define C_   256
#define LP_  128      // L/2 after maxpool
#define DI_  512      // d_inner
#define DS_  16       // d_state

// ---------------------------------------------------------------------------
// embed gather: e[b, l*E + j] = embed[x[b,l], j]
// ---------------------------------------------------------------------------
__global__ __launch_bounds__(64) void embed_k(const int* __restrict__ x,
                                              const float* __restrict__ emb,
                                              float* __restrict__ e) {
  int bl = blockIdx.x;                       // b*256 + l
  int idx = x[bl];
  const float2* src = (const float2*)(emb + (size_t)idx * E_);
  float2* dst = (float2*)(e + (size_t)bl * E_);
  dst[threadIdx.x] = src[threadIdx.x];
}

// ---------------------------------------------------------------------------
// Generic tiled GEMM: C[m,n] = sum_k A[m,k] * W[n,k]  (both row-major, K-contig)
// BM=BN=64, BK=32, 256 threads, 4x4 micro-tile, fp64 accumulation.
// gridDim.z > 1 => split-K: raw double partials to (double*)Cout.
// ---------------------------------------------------------------------------
__global__ __launch_bounds__(256) void gemm_k(const float* __restrict__ A,
                                              const float* __restrict__ W,
                                              const float* __restrict__ bias,
                                              float* __restrict__ Cout,
                                              int M, int N, int K, int kChunk, int act) {
  __shared__ __align__(16) float As[32][64];   // [k][m]
  __shared__ __align__(16) float Ws[32][64];   // [k][n]
  const int tid = threadIdx.x;
  const int row = tid >> 2;                    // 0..63
  const int seg = (tid & 3) * 8;               // 0,8,16,24
  const int tx = tid & 15, ty = tid >> 4;
  const int bn = blockIdx.x * 64, bm = blockIdx.y * 64;
  const int kStart = blockIdx.z * kChunk;

  double acc[4][4];
#pragma unroll
  for (int i = 0; i < 4; ++i)
#pragma unroll
    for (int j = 0; j < 4; ++j) acc[i][j] = 0.0;

  const float* Arow = A + (size_t)(bm + row) * K + seg;
  const float* Wrow = W + (size_t)(bn + row) * K + seg;

  for (int k0 = kStart; k0 < kStart + kChunk; k0 += 32) {
    float4 a0 = *(const float4*)(Arow + k0);
    float4 a1 = *(const float4*)(Arow + k0 + 4);
    float4 w0 = *(const float4*)(Wrow + k0);
    float4 w1 = *(const float4*)(Wrow + k0 + 4);
    __syncthreads();   // previous iteration's compute done before overwrite
    As[seg + 0][row] = a0.x; As[seg + 1][row] = a0.y;
    As[seg + 2][row] = a0.z; As[seg + 3][row] = a0.w;
    As[seg + 4][row] = a1.x; As[seg + 5][row] = a1.y;
    As[seg + 6][row] = a1.z; As[seg + 7][row] = a1.w;
    Ws[seg + 0][row] = w0.x; Ws[seg + 1][row] = w0.y;
    Ws[seg + 2][row] = w0.z; Ws[seg + 3][row] = w0.w;
    Ws[seg + 4][row] = w1.x; Ws[seg + 5][row] = w1.y;
    Ws[seg + 6][row] = w1.z; Ws[seg + 7][row] = w1.w;
    __syncthreads();
#pragma unroll
    for (int kk = 0; kk < 32; ++kk) {
      float4 av = *(const float4*)&As[kk][ty * 4];
      float4 wv = *(const float4*)&Ws[kk][tx * 4];
      float a[4] = {av.x, av.y, av.z, av.w};
      float w[4] = {wv.x, wv.y, wv.z, wv.w};
#pragma unroll
      for (int i = 0; i < 4; ++i)
#pragma unroll
        for (int j = 0; j < 4; ++j) acc[i][j] += (double)a[i] * (double)w[j];
    }
  }

  if (gridDim.z > 1) {
    double* P = (double*)Cout;
    size_t zoff = (size_t)blockIdx.z * M * N;
#pragma unroll
    for (int i = 0; i < 4; ++i) {
      int m = bm + ty * 4 + i;
      double* dst = P + zoff + (size_t)m * N + bn + tx * 4;
      dst[0] = acc[i][0]; dst[1] = acc[i][1];
      dst[2] = acc[i][2]; dst[3] = acc[i][3];
    }
  } else {
#pragma unroll
    for (int i = 0; i < 4; ++i) {
      int m = bm + ty * 4 + i;
      float4 o;
      float* op = &o.x;
#pragma unroll
      for (int j = 0; j < 4; ++j) {
        int n = bn + tx * 4 + j;
        double v = acc[i][j];
        if (bias) v += (double)bias[n];
        if (act) v = v > 0.0 ? v : 0.0;
        op[j] = (float)v;
      }
      *(float4*)(Cout + (size_t)m * N + bn + tx * 4) = o;
    }
  }
}

// ---------------------------------------------------------------------------
// split-K reduce + bias + relu (enc1).  N must be pow2 (2048).
// ---------------------------------------------------------------------------
__global__ __launch_bounds__(256) void reduce_k(const double* __restrict__ P,
                                                const float* __restrict__ bias,
                                                float* __restrict__ Out,
                                                int MN, int N, int S) {
  int i = blockIdx.x * 256 + threadIdx.x;
  if (i >= MN) return;
  double s = 0.0;
  for (int z = 0; z < S; ++z) s += P[(size_t)z * MN + i];
  s += (double)bias[i & (N - 1)];
  Out[i] = (float)(s > 0.0 ? s : 0.0);
}

// ---------------------------------------------------------------------------
// weight preps: conv_w (C,E,5) -> wT[(e*5+t)*C + c]; x_proj_w (48,512) -> padded (64,512)
// ---------------------------------------------------------------------------
__global__ __launch_bounds__(256) void prep_convw_k(const float* __restrict__ cw,
                                                    float* __restrict__ wT) {
  int et = blockIdx.x;                 // 0..639 = e*5+t
  int c = threadIdx.x;                 // 0..255
  wT[et * 256 + c] = cw[c * 640 + et];
}

__global__ __launch_bounds__(256) void prep_xpw_k(const float* __restrict__ w,
                                                  float* __restrict__ wp) {
  int i = blockIdx.x * 256 + threadIdx.x;   // 0..32767
  int n = i >> 9, k = i & 511;
  wp[i] = (n < 48) ? w[n * 512 + k] : 0.0f;
}

// ---------------------------------------------------------------------------
// conv1d(k=5,pad=2) + bias + relu + maxpool2 -> xs (B, 128, 256)
// input h2 viewed as (b, l, e) with e contiguous.
// ---------------------------------------------------------------------------
__global__ __launch_bounds__(256) void conv_pool_k(const float* __restrict__ h2,
                                                   const float* __restrict__ wT,
                                                   const float* __restrict__ cb,
                                                   float* __restrict__ xs) {
  __shared__ float in[20][128];
  int b = blockIdx.x;
  int l0 = blockIdx.y * 16;
  for (int idx = threadIdx.x; idx < 20 * 128; idx += 256) {
    int r = idx >> 7, e = idx & 127;
    int l = l0 - 2 + r;
    in[r][e] = (l >= 0 && l < L_) ? h2[((size_t)b * L_ + l) * E_ + e] : 0.0f;
  }
  __syncthreads();
  int c = threadIdx.x;                 // output channel
  double acc[16];
  double bc = (double)cb[c];
#pragma unroll
  for (int l = 0; l < 16; ++l) acc[l] = bc;
  for (int e = 0; e < 128; ++e) {
    float vin[20];
#pragma unroll
    for (int r = 0; r < 20; ++r) vin[r] = in[r][e];
#pragma unroll
    for (int t = 0; t < 5; ++t) {
      double w = (double)wT[(e * 5 + t) * 256 + c];
#pragma unroll
      for (int l = 0; l < 16; ++l) acc[l] += (double)vin[l + t] * w;
    }
  }
  int l2 = l0 >> 1;
#pragma unroll
  for (int p = 0; p < 8; ++p) {
    double v0 = acc[2 * p]     > 0.0 ? acc[2 * p]     : 0.0;
    double v1 = acc[2 * p + 1] > 0.0 ? acc[2 * p + 1] : 0.0;
    xs[((size_t)b * LP_ + l2 + p) * C_ + c] = (float)(v0 > v1 ? v0 : v1);
  }
}

// ---------------------------------------------------------------------------
// depthwise causal conv4 + SiLU on u = xz[:, :512] -> u2
// ---------------------------------------------------------------------------
__global__ __launch_bounds__(512) void dwconv_k(const float* __restrict__ xz,
                                                const float* __restrict__ cw,
                                                const float* __restrict__ cb,
                                                float* __restrict__ u2) {
  int m = blockIdx.x;                  // b*128 + t
  int t = m & (LP_ - 1);
  int d = threadIdx.x;
  float4 w = *(const float4*)(cw + d * 4);
  const float* base = xz + (size_t)m * (2 * DI_) + d;
  double pre = (double)cb[d];
  if (t >= 3) {
    pre += (double)base[-3 * 2 * DI_] * (double)w.x;
    pre += (double)base[-2 * 2 * DI_] * (double)w.y;
    pre += (double)base[-1 * 2 * DI_] * (double)w.z;
    pre += (double)base[0]            * (double)w.w;
  } else {
    const float wv[4] = {w.x, w.y, w.z, w.w};
    for (int j = 0; j < 4; ++j) {
      int tt = t - 3 + j;
      if (tt >= 0) pre += (double)base[(j - 3) * 2 * DI_] * (double)wv[j];
    }
  }
  double s = pre / (1.0 + exp(-pre));  // silu
  u2[(size_t)m * DI_ + d] = (float)s;
}

// ---------------------------------------------------------------------------
// delta = softplus(dt @ dt_proj_w.T + dt_proj_b); dt = xdbl[:, :16] (row stride 64)
// ---------------------------------------------------------------------------
__global__ __launch_bounds__(512) void delta_k(const float* __restrict__ xdbl,
                                               const float* __restrict__ dtw,
                                               const float* __restrict__ dtb,
                                               float* __restrict__ delta) {
  __shared__ float dt[16];
  int m = blockIdx.x;
  int d = threadIdx.x;
  if (d < 16) dt[d] = xdbl[(size_t)m * 64 + d];
  __syncthreads();
  double acc = (double)dtb[d];
  const float* wr = dtw + d * 16;
#pragma unroll
  for (int r = 0; r < 16; ++r) acc += (double)dt[r] * (double)wr[r];
  double sp = (acc > 0.0 ? acc : 0.0) + log1p(exp(-fabs(acc)));
  delta[(size_t)m * DI_ + d] = (float)sp;
}

// ---------------------------------------------------------------------------
// selective scan + D skip + z gate -> yg (8192, 512)
// dA_n = exp(dl*A_n) computed as r^(n+1)*(1 + dl*c_n), r = exp(-dl),
// c_n = A_n + (n+1) (exact fp64 residual of A_n vs -(n+1)); error ~1e-13 rel.
// ---------------------------------------------------------------------------
__global__ __launch_bounds__(256) void scan_k(const float* __restrict__ delta,
                                              const float* __restrict__ u2,
                                              const float* __restrict__ xz,
                                              const float* __restrict__ xdbl,
                                              const float* __restrict__ A_log,
                                              const float* __restrict__ Dp,
                                              float* __restrict__ yg) {
  int b = blockIdx.x >> 1;
  int d = ((blockIdx.x & 1) << 8) + threadIdx.x;
  double cn[16];
#pragma unroll
  for (int n = 0; n < 16; ++n) {
    double Ar = -exp((double)A_log[d * 16 + n]);
    cn[n] = Ar + (double)(n + 1);
  }
  double Dd = (double)Dp[d];
  double h[16];
#pragma unroll
  for (int n = 0; n < 16; ++n) h[n] = 0.0;
  for (int t = 0; t < LP_; ++t) {
    size_t m = (size_t)b * LP_ + t;
    double dl = (double)delta[m * DI_ + d];
    double uu = (double)u2[m * DI_ + d];
    double zz = (double)xz[m * (2 * DI_) + DI_ + d];
    const float* bc = xdbl + m * 64 + 16;   // B[0:16], C[16:32]
    double du = dl * uu;
    double r = exp(-dl);
    double p = 1.0;
    double y = 0.0;
#pragma unroll
    for (int n = 0; n < 16; ++n) {
      p *= r;                                // r^(n+1)
      double dA = p + p * (dl * cn[n]);      // first-order exact-A correction
      h[n] = dA * h[n] + du * (double)bc[n];
      y += h[n] * (double)bc[16 + n];
    }
    double o = (y + uu * Dd) * (zz / (1.0 + exp(-zz)));
    yg[m * DI_ + d] = (float)o;
  }
}

// ---------------------------------------------------------------------------
// mean over t + fc head -> out (64, 10)
// ---------------------------------------------------------------------------
__global__ __launch_bounds__(256) void meanfc_k(const float* __restrict__ mout,
                                                const float* __restrict__ fcw,
                                                const float* __restrict__ fcb,
                                                float* __restrict__ out) {
  __shared__ double pooled[256];
  int b = blockIdx.x;
  int c = threadIdx.x;
  double s = 0.0;
  for (int t = 0; t < LP_; ++t) s += (double)mout[((size_t)b * LP_ + t) * C_ + c];
  pooled[c] = s * (1.0 / 128.0);
  __syncthreads();
  if (c < 10) {
    double acc = (double)fcb[c];
    for (int k = 0; k < 256; ++k) acc += pooled[k] * (double)fcw[c * 256 + k];
    out[b * 10 + c] = (float)acc;
  }
}

// ---------------------------------------------------------------------------
extern "C" void kernel_launch(void* const* d_in, const int* in_sizes, int n_in,
                              void* d_out, int out_size, void* d_ws, size_t ws_size,
                              hipStream_t stream) {
  const int*   x         = (const int*)d_in[0];
  const float* embed     = (const float*)d_in[1];
  const float* enc_w1    = (const float*)d_in[2];
  const float* enc_b1    = (const float*)d_in[3];
  const float* enc_w2    = (const float*)d_in[4];
  const float* enc_b2    = (const float*)d_in[5];
  const float* conv_w    = (const float*)d_in[6];
  const float* conv_b    = (const float*)d_in[7];
  const float* in_proj_w = (const float*)d_in[8];
  const float* conv1d_w  = (const float*)d_in[9];
  const float* conv1d_b  = (const float*)d_in[10];
  const float* x_proj_w  = (const float*)d_in[11];
  const float* dt_proj_w = (const float*)d_in[12];
  const float* dt_proj_b = (const float*)d_in[13];
  const float* A_log     = (const float*)d_in[14];
  const float* Dp        = (const float*)d_in[15];
  const float* out_proj_w= (const float*)d_in[16];
  const float* fc_w      = (const float*)d_in[17];
  const float* fc_b      = (const float*)d_in[18];
  float* out = (float*)d_out;

  char* ws = (char*)d_ws;
  size_t off = 0;
  auto alloc = [&](size_t bytes) {
    char* p = ws + off;
    off += (bytes + 255) & ~(size_t)255;
    return p;
  };
  float*  e    = (float*) alloc(2097152ull * 4);  // (64, 32768)
  double* P    = (double*)alloc(1048576ull * 8);  // split-K partials (8,64,2048)
  float*  h1   = (float*) alloc(131072ull  * 4);  // (64, 2048)
  float*  h2   = (float*) alloc(2097152ull * 4);  // (64, 32768)
  float*  wT   = (float*) alloc(163840ull  * 4);  // conv weights (e*5+t, c)
  float*  xs   = (float*) alloc(2097152ull * 4);  // (8192, 256)
  float*  xz   = (float*) alloc(8388608ull * 4);  // (8192, 1024)
  float*  u2   = (float*) alloc(4194304ull * 4);  // (8192, 512)
  float*  xpw  = (float*) alloc(32768ull   * 4);  // padded x_proj_w (64, 512)
  float*  xdbl = (float*) alloc(524288ull  * 4);  // (8192, 64)
  float*  dl   = (float*) alloc(4194304ull * 4);  // delta (8192, 512)
  float*  yg   = (float*) alloc(4194304ull * 4);  // gated y (8192, 512)
  float*  mout = (float*) alloc(2097152ull * 4);  // (8192, 256)
  (void)ws_size; (void)in_sizes; (void)n_in; (void)out_size;

  embed_k<<<16384, 64, 0, stream>>>(x, embed, e);
  prep_convw_k<<<640, 256, 0, stream>>>(conv_w, wT);
  prep_xpw_k<<<128, 256, 0, stream>>>(x_proj_w, xpw);

  // enc1: (64,2048,K=32768), split-K=8 -> 256 blocks
  gemm_k<<<dim3(32, 1, 8), 256, 0, stream>>>(e, enc_w1, nullptr, (float*)P,
                                             64, 2048, 32768, 4096, 0);
  reduce_k<<<512, 256, 0, stream>>>(P, enc_b1, h1, 131072, 2048, 8);

  // enc2: (64,32768,K=2048), bias+relu fused -> 512 blocks
  gemm_k<<<dim3(512, 1, 1), 256, 0, stream>>>(h1, enc_w2, enc_b2, h2,
                                              64, 32768, 2048, 2048, 1);

  conv_pool_k<<<dim3(64, 16), 256, 0, stream>>>(h2, wT, conv_b, xs);

  // in_proj: (8192,1024,K=256)
  gemm_k<<<dim3(16, 128, 1), 256, 0, stream>>>(xs, in_proj_w, nullptr, xz,
                                               8192, 1024, 256, 256, 0);

  dwconv_k<<<8192, 512, 0, stream>>>(xz, conv1d_w, conv1d_b, u2);

  // x_proj (padded to N=64): (8192,64,K=512)
  gemm_k<<<dim3(1, 128, 1), 256, 0, stream>>>(u2, xpw, nullptr, xdbl,
                                              8192, 64, 512, 512, 0);

  delta_k<<<8192, 512, 0, stream>>>(xdbl, dt_proj_w, dt_proj_b, dl);

  scan_k<<<128, 256, 0, stream>>>(dl, u2, xz, xdbl, A_log, Dp, yg);

  // out_proj: (8192,256,K=512)
  gemm_k<<<dim3(4, 128, 1), 256, 0, stream>>>(yg, out_proj_w, nullptr, mout,
                                              8192, 256, 512, 512, 0);

  meanfc_k<<<64, 256, 0, stream>>>(mout, fc_w, fc_b, out);
}

// Round 2
// 1050.452 us; speedup vs baseline: 1.4147x; 1.4147x over previous
//
#include <hip/hip_runtime.h>
#include <cstddef>
#include <cstdint>

// Problem constants
#define B_   64
#define L_   256
#define E_   128
#define H_   2048
#define C_   256
#define LP_  128      // L/2 after maxpool
#define DI_  512      // d_inner
#define DS_  16       // d_state

// ---------------------------------------------------------------------------
// embed gather: e[b, l*E + j] = embed[x[b,l], j]
// ---------------------------------------------------------------------------
__global__ __launch_bounds__(64) void embed_k(const int* __restrict__ x,
                                              const float* __restrict__ emb,
                                              float* __restrict__ e) {
  int bl = blockIdx.x;                       // b*256 + l
  int idx = x[bl];
  const float2* src = (const float2*)(emb + (size_t)idx * E_);
  float2* dst = (float2*)(e + (size_t)bl * E_);
  dst[threadIdx.x] = src[threadIdx.x];
}

// ---------------------------------------------------------------------------
// Generic tiled GEMM: C[m,n] = sum_k A[m,k] * W[n,k]  (both row-major, K-contig)
// BM=BN=64, BK=32, 256 threads, 4x4 micro-tile, fp32 accumulation.
// gridDim.z > 1 => split-K: fp32 partials to Cout (z-major).
// ---------------------------------------------------------------------------
__global__ __launch_bounds__(256) void gemm_k(const float* __restrict__ A,
                                              const float* __restrict__ W,
                                              const float* __restrict__ bias,
                                              float* __restrict__ Cout,
                                              int M, int N, int K, int kChunk, int act) {
  __shared__ __align__(16) float As[32][64];   // [k][m]
  __shared__ __align__(16) float Ws[32][64];   // [k][n]
  const int tid = threadIdx.x;
  const int row = tid >> 2;                    // 0..63
  const int seg = (tid & 3) * 8;               // 0,8,16,24
  const int tx = tid & 15, ty = tid >> 4;
  const int bn = blockIdx.x * 64, bm = blockIdx.y * 64;
  const int kStart = blockIdx.z * kChunk;

  float acc[4][4];
#pragma unroll
  for (int i = 0; i < 4; ++i)
#pragma unroll
    for (int j = 0; j < 4; ++j) acc[i][j] = 0.0f;

  const float* Arow = A + (size_t)(bm + row) * K + seg;
  const float* Wrow = W + (size_t)(bn + row) * K + seg;

  for (int k0 = kStart; k0 < kStart + kChunk; k0 += 32) {
    float4 a0 = *(const float4*)(Arow + k0);
    float4 a1 = *(const float4*)(Arow + k0 + 4);
    float4 w0 = *(const float4*)(Wrow + k0);
    float4 w1 = *(const float4*)(Wrow + k0 + 4);
    __syncthreads();   // previous iteration's compute done before overwrite
    As[seg + 0][row] = a0.x; As[seg + 1][row] = a0.y;
    As[seg + 2][row] = a0.z; As[seg + 3][row] = a0.w;
    As[seg + 4][row] = a1.x; As[seg + 5][row] = a1.y;
    As[seg + 6][row] = a1.z; As[seg + 7][row] = a1.w;
    Ws[seg + 0][row] = w0.x; Ws[seg + 1][row] = w0.y;
    Ws[seg + 2][row] = w0.z; Ws[seg + 3][row] = w0.w;
    Ws[seg + 4][row] = w1.x; Ws[seg + 5][row] = w1.y;
    Ws[seg + 6][row] = w1.z; Ws[seg + 7][row] = w1.w;
    __syncthreads();
#pragma unroll
    for (int kk = 0; kk < 32; ++kk) {
      float4 av = *(const float4*)&As[kk][ty * 4];
      float4 wv = *(const float4*)&Ws[kk][tx * 4];
      float a[4] = {av.x, av.y, av.z, av.w};
      float w[4] = {wv.x, wv.y, wv.z, wv.w};
#pragma unroll
      for (int i = 0; i < 4; ++i)
#pragma unroll
        for (int j = 0; j < 4; ++j) acc[i][j] = fmaf(a[i], w[j], acc[i][j]);
    }
  }

  if (gridDim.z > 1) {
    float* P = Cout + (size_t)blockIdx.z * M * N;
#pragma unroll
    for (int i = 0; i < 4; ++i) {
      int m = bm + ty * 4 + i;
      float4 o = {acc[i][0], acc[i][1], acc[i][2], acc[i][3]};
      *(float4*)(P + (size_t)m * N + bn + tx * 4) = o;
    }
  } else {
#pragma unroll
    for (int i = 0; i < 4; ++i) {
      int m = bm + ty * 4 + i;
      float4 o;
      float* op = &o.x;
#pragma unroll
      for (int j = 0; j < 4; ++j) {
        int n = bn + tx * 4 + j;
        float v = acc[i][j];
        if (bias) v += bias[n];
        if (act) v = v > 0.0f ? v : 0.0f;
        op[j] = v;
      }
      *(float4*)(Cout + (size_t)m * N + bn + tx * 4) = o;
    }
  }
}

// ---------------------------------------------------------------------------
// split-K reduce + bias + relu (enc1).  N must be pow2 (2048).
// ---------------------------------------------------------------------------
__global__ __launch_bounds__(256) void reduce_k(const float* __restrict__ P,
                                                const float* __restrict__ bias,
                                                float* __restrict__ Out,
                                                int MN, int N, int S) {
  int i = blockIdx.x * 256 + threadIdx.x;
  if (i >= MN) return;
  float s = 0.0f;
  for (int z = 0; z < S; ++z) s += P[(size_t)z * MN + i];
  s += bias[i & (N - 1)];
  Out[i] = s > 0.0f ? s : 0.0f;
}

// ---------------------------------------------------------------------------
// weight preps: conv_w (C,E,5) -> wT[(e*5+t)*C + c]; x_proj_w (48,512) -> padded (64,512)
// ---------------------------------------------------------------------------
__global__ __launch_bounds__(256) void prep_convw_k(const float* __restrict__ cw,
                                                    float* __restrict__ wT) {
  int et = blockIdx.x;                 // 0..639 = e*5+t
  int c = threadIdx.x;                 // 0..255
  wT[et * 256 + c] = cw[c * 640 + et];
}

__global__ __launch_bounds__(256) void prep_xpw_k(const float* __restrict__ w,
                                                  float* __restrict__ wp) {
  int i = blockIdx.x * 256 + threadIdx.x;   // 0..32767
  int n = i >> 9, k = i & 511;
  wp[i] = (n < 48) ? w[n * 512 + k] : 0.0f;
}

// ---------------------------------------------------------------------------
// conv1d(k=5,pad=2) + bias + relu + maxpool2 -> xs (B, 128, 256)
// input h2 viewed as (b, l, e) with e contiguous.
// ---------------------------------------------------------------------------
__global__ __launch_bounds__(256) void conv_pool_k(const float* __restrict__ h2,
                                                   const float* __restrict__ wT,
                                                   const float* __restrict__ cb,
                                                   float* __restrict__ xs) {
  __shared__ float in[20][128];
  int b = blockIdx.x;
  int l0 = blockIdx.y * 16;
  for (int idx = threadIdx.x; idx < 20 * 128; idx += 256) {
    int r = idx >> 7, e = idx & 127;
    int l = l0 - 2 + r;
    in[r][e] = (l >= 0 && l < L_) ? h2[((size_t)b * L_ + l) * E_ + e] : 0.0f;
  }
  __syncthreads();
  int c = threadIdx.x;                 // output channel
  float acc[16];
  float bc = cb[c];
#pragma unroll
  for (int l = 0; l < 16; ++l) acc[l] = bc;
  for (int e = 0; e < 128; ++e) {
    float vin[20];
#pragma unroll
    for (int r = 0; r < 20; ++r) vin[r] = in[r][e];
#pragma unroll
    for (int t = 0; t < 5; ++t) {
      float w = wT[(e * 5 + t) * 256 + c];
#pragma unroll
      for (int l = 0; l < 16; ++l) acc[l] = fmaf(vin[l + t], w, acc[l]);
    }
  }
  int l2 = l0 >> 1;
#pragma unroll
  for (int p = 0; p < 8; ++p) {
    float v0 = acc[2 * p]     > 0.0f ? acc[2 * p]     : 0.0f;
    float v1 = acc[2 * p + 1] > 0.0f ? acc[2 * p + 1] : 0.0f;
    xs[((size_t)b * LP_ + l2 + p) * C_ + c] = v0 > v1 ? v0 : v1;
  }
}

// ---------------------------------------------------------------------------
// depthwise causal conv4 + SiLU on u = xz[:, :512] -> u2
// ---------------------------------------------------------------------------
__global__ __launch_bounds__(512) void dwconv_k(const float* __restrict__ xz,
                                               const float* __restrict__ cw,
                                               const float* __restrict__ cb,
                                               float* __restrict__ u2) {
  int m = blockIdx.x;                  // b*128 + t
  int t = m & (LP_ - 1);
  int d = threadIdx.x;
  float4 w = *(const float4*)(cw + d * 4);
  const float* base = xz + (size_t)m * (2 * DI_) + d;
  float pre = cb[d];
  if (t >= 3) {
    pre = fmaf(base[-3 * 2 * DI_], w.x, pre);
    pre = fmaf(base[-2 * 2 * DI_], w.y, pre);
    pre = fmaf(base[-1 * 2 * DI_], w.z, pre);
    pre = fmaf(base[0],            w.w, pre);
  } else {
    const float wv[4] = {w.x, w.y, w.z, w.w};
    for (int j = 0; j < 4; ++j) {
      int tt = t - 3 + j;
      if (tt >= 0) pre = fmaf(base[(j - 3) * 2 * DI_], wv[j], pre);
    }
  }
  float s = pre / (1.0f + __expf(-pre));  // silu
  u2[(size_t)m * DI_ + d] = s;
}

// ---------------------------------------------------------------------------
// delta = softplus(dt @ dt_proj_w.T + dt_proj_b); dt = xdbl[:, :16] (row stride 64)
// ---------------------------------------------------------------------------
__global__ __launch_bounds__(512) void delta_k(const float* __restrict__ xdbl,
                                               const float* __restrict__ dtw,
                                               const float* __restrict__ dtb,
                                               float* __restrict__ delta) {
  __shared__ float dt[16];
  int m = blockIdx.x;
  int d = threadIdx.x;
  if (d < 16) dt[d] = xdbl[(size_t)m * 64 + d];
  __syncthreads();
  float acc = dtb[d];
  const float* wr = dtw + d * 16;
#pragma unroll
  for (int r = 0; r < 16; ++r) acc = fmaf(dt[r], wr[r], acc);
  // softplus(x) = max(x,0) + log1p(exp(-|x|))
  float sp = (acc > 0.0f ? acc : 0.0f) + log1pf(__expf(-fabsf(acc)));
  delta[(size_t)m * DI_ + d] = sp;
}

// ---------------------------------------------------------------------------
// selective scan + D skip + z gate -> yg (8192, 512)
// 16 lanes per (b,d) channel — one lane per state n; shfl_xor width-16 reduce.
// ---------------------------------------------------------------------------
__global__ __launch_bounds__(256) void scan_k(const float* __restrict__ delta,
                                              const float* __restrict__ u2,
                                              const float* __restrict__ xz,
                                              const float* __restrict__ xdbl,
                                              const float* __restrict__ A_log,
                                              const float* __restrict__ Dp,
                                              float* __restrict__ yg) {
  int tid = threadIdx.x;
  int n = tid & 15;                    // state index
  int ch = tid >> 4;                   // channel within block (0..15)
  int b = blockIdx.x >> 5;             // 32 blocks per batch row
  int d = ((blockIdx.x & 31) << 4) + ch;
  float An = -__expf(A_log[d * 16 + n]);
  float Dd = Dp[d];
  float h = 0.0f;
  const size_t mBase = (size_t)b * LP_;
  for (int t = 0; t < LP_; ++t) {
    size_t m = mBase + t;
    float dl = delta[m * DI_ + d];     // broadcast across 16 lanes
    float uu = u2[m * DI_ + d];
    float Bn = xdbl[m * 64 + 16 + n];
    float Cn = xdbl[m * 64 + 32 + n];
    float dA = __expf(dl * An);
    h = fmaf(dA, h, (dl * uu) * Bn);
    float y = h * Cn;
    y += __shfl_xor(y, 1, 16);
    y += __shfl_xor(y, 2, 16);
    y += __shfl_xor(y, 4, 16);
    y += __shfl_xor(y, 8, 16);
    if (n == 0) {
      float zz = xz[m * (2 * DI_) + DI_ + d];
      float g = zz / (1.0f + __expf(-zz));
      yg[m * DI_ + d] = fmaf(uu, Dd, y) * g;
    }
  }
}

// ---------------------------------------------------------------------------
// mean over t + fc head -> out (64, 10)
// ---------------------------------------------------------------------------
__global__ __launch_bounds__(256) void meanfc_k(const float* __restrict__ mout,
                                               const float* __restrict__ fcw,
                                               const float* __restrict__ fcb,
                                               float* __restrict__ out) {
  __shared__ float pooled[256];
  int b = blockIdx.x;
  int c = threadIdx.x;
  float s = 0.0f;
  for (int t = 0; t < LP_; ++t) s += mout[((size_t)b * LP_ + t) * C_ + c];
  pooled[c] = s * (1.0f / 128.0f);
  __syncthreads();
  if (c < 10) {
    float acc = fcb[c];
    for (int k = 0; k < 256; ++k) acc = fmaf(pooled[k], fcw[c * 256 + k], acc);
    out[b * 10 + c] = acc;
  }
}

// ---------------------------------------------------------------------------
extern "C" void kernel_launch(void* const* d_in, const int* in_sizes, int n_in,
                              void* d_out, int out_size, void* d_ws, size_t ws_size,
                              hipStream_t stream) {
  const int*   x         = (const int*)d_in[0];
  const float* embed     = (const float*)d_in[1];
  const float* enc_w1    = (const float*)d_in[2];
  const float* enc_b1    = (const float*)d_in[3];
  const float* enc_w2    = (const float*)d_in[4];
  const float* enc_b2    = (const float*)d_in[5];
  const float* conv_w    = (const float*)d_in[6];
  const float* conv_b    = (const float*)d_in[7];
  const float* in_proj_w = (const float*)d_in[8];
  const float* conv1d_w  = (const float*)d_in[9];
  const float* conv1d_b  = (const float*)d_in[10];
  const float* x_proj_w  = (const float*)d_in[11];
  const float* dt_proj_w = (const float*)d_in[12];
  const float* dt_proj_b = (const float*)d_in[13];
  const float* A_log     = (const float*)d_in[14];
  const float* Dp        = (const float*)d_in[15];
  const float* out_proj_w= (const float*)d_in[16];
  const float* fc_w      = (const float*)d_in[17];
  const float* fc_b      = (const float*)d_in[18];
  float* out = (float*)d_out;

  char* ws = (char*)d_ws;
  size_t off = 0;
  auto alloc = [&](size_t bytes) {
    char* p = ws + off;
    off += (bytes + 255) & ~(size_t)255;
    return p;
  };
  float*  e    = (float*) alloc(2097152ull * 4);  // (64, 32768)
  float*  P    = (float*) alloc(2097152ull * 4);  // split-K partials (16,64,2048)
  float*  h1   = (float*) alloc(131072ull  * 4);  // (64, 2048)
  float*  h2   = (float*) alloc(2097152ull * 4);  // (64, 32768)
  float*  wT   = (float*) alloc(163840ull  * 4);  // conv weights (e*5+t, c)
  float*  xs   = (float*) alloc(2097152ull * 4);  // (8192, 256)
  float*  xz   = (float*) alloc(8388608ull * 4);  // (8192, 1024)
  float*  u2   = (float*) alloc(4194304ull * 4);  // (8192, 512)
  float*  xpw  = (float*) alloc(32768ull   * 4);  // padded x_proj_w (64, 512)
  float*  xdbl = (float*) alloc(524288ull  * 4);  // (8192, 64)
  float*  dl   = (float*) alloc(4194304ull * 4);  // delta (8192, 512)
  float*  yg   = (float*) alloc(4194304ull * 4);  // gated y (8192, 512)
  float*  mout = (float*) alloc(2097152ull * 4);  // (8192, 256)
  (void)ws_size; (void)in_sizes; (void)n_in; (void)out_size;

  embed_k<<<16384, 64, 0, stream>>>(x, embed, e);
  prep_convw_k<<<640, 256, 0, stream>>>(conv_w, wT);
  prep_xpw_k<<<128, 256, 0, stream>>>(x_proj_w, xpw);

  // enc1: (64,2048,K=32768), split-K=16 -> 512 blocks
  gemm_k<<<dim3(32, 1, 16), 256, 0, stream>>>(e, enc_w1, nullptr, P,
                                              64, 2048, 32768, 2048, 0);
  reduce_k<<<512, 256, 0, stream>>>(P, enc_b1, h1, 131072, 2048, 16);

  // enc2: (64,32768,K=2048), bias+relu fused -> 512 blocks
  gemm_k<<<dim3(512, 1, 1), 256, 0, stream>>>(h1, enc_w2, enc_b2, h2,
                                              64, 32768, 2048, 2048, 1);

  conv_pool_k<<<dim3(64, 16), 256, 0, stream>>>(h2, wT, conv_b, xs);

  // in_proj: (8192,1024,K=256)
  gemm_k<<<dim3(16, 128, 1), 256, 0, stream>>>(xs, in_proj_w, nullptr, xz,
                                               8192, 1024, 256, 256, 0);

  dwconv_k<<<8192, 512, 0, stream>>>(xz, conv1d_w, conv1d_b, u2);

  // x_proj (padded to N=64): (8192,64,K=512)
  gemm_k<<<dim3(1, 128, 1), 256, 0, stream>>>(u2, xpw, nullptr, xdbl,
                                              8192, 64, 512, 512, 0);

  delta_k<<<8192, 512, 0, stream>>>(xdbl, dt_proj_w, dt_proj_b, dl);

  scan_k<<<2048, 256, 0, stream>>>(dl, u2, xz, xdbl, A_log, Dp, yg);

  // out_proj: (8192,256,K=512)
  gemm_k<<<dim3(4, 128, 1), 256, 0, stream>>>(yg, out_proj_w, nullptr, mout,
                                              8192, 256, 512, 512, 0);

  meanfc_k<<<64, 256, 0, stream>>>(mout, fc_w, fc_b, out);
}

// Round 3
// 938.047 us; speedup vs baseline: 1.5843x; 1.1198x over previous
//
#include <hip/hip_runtime.h>
#include <cstddef>
#include <cstdint>

// Problem constants
#define B_   64
#define L_   256
#define E_   128
#define H_   2048
#define C_   256
#define LP_  128      // L/2 after maxpool
#define DI_  512      // d_inner
#define DS_  16       // d_state

typedef __attribute__((ext_vector_type(8))) short s16x8;
typedef __attribute__((ext_vector_type(4))) float f32x4;

// fp32 -> bf16 round-to-nearest-even (bit-level; inputs are finite/small)
__device__ __forceinline__ short f2bf(float x) {
  uint32_t u = __float_as_uint(x);
  uint32_t r = (u + 0x7FFFu + ((u >> 16) & 1u)) >> 16;
  return (short)r;
}
__device__ __forceinline__ float bf2f(short h) {
  return __uint_as_float(((uint32_t)(uint16_t)h) << 16);
}

// ---------------------------------------------------------------------------
// embed gather: e[b, l*E + j] = embed[x[b,l], j]
// ---------------------------------------------------------------------------
__global__ __launch_bounds__(64) void embed_k(const int* __restrict__ x,
                                              const float* __restrict__ emb,
                                              float* __restrict__ e) {
  int bl = blockIdx.x;                       // b*256 + l
  int idx = x[bl];
  const float2* src = (const float2*)(emb + (size_t)idx * E_);
  float2* dst = (float2*)(e + (size_t)bl * E_);
  dst[threadIdx.x] = src[threadIdx.x];
}

// ---------------------------------------------------------------------------
// MFMA split-bf16 GEMM: C[m,n] = sum_k A[m,k] * W[n,k]  (row-major, K-contig)
// Each fp32 = bf16(hi) + bf16(lo); acc += Ahi*Whi + Ahi*Wlo + Alo*Whi.
// BM=BN=64, BK=32, 256 threads = 4 waves, wave tile 16(M)x64(N),
// v_mfma_f32_16x16x32_bf16. gridDim.z>1 => split-K fp32 partials.
// ---------------------------------------------------------------------------
__global__ __launch_bounds__(256) void gemm_mfma_k(const float* __restrict__ A,
                                                   const float* __restrict__ W,
                                                   const float* __restrict__ bias,
                                                   float* __restrict__ Cout,
                                                   int M, int N, int K, int kChunk,
                                                   int act) {
  // stride 40 shorts = 80 B (16B-aligned rows, <=2-way banks on frag reads)
  __shared__ __align__(16) short Ahi[64][40];
  __shared__ __align__(16) short Alo[64][40];
  __shared__ __align__(16) short Whi[64][40];
  __shared__ __align__(16) short Wlo[64][40];

  const int tid = threadIdx.x;
  const int r   = tid >> 2;                  // staging row 0..63
  const int seg = (tid & 3) * 8;             // staging k-seg 0/8/16/24
  const int lane = tid & 63;
  const int wv   = tid >> 6;                 // wave 0..3 -> M-strip
  const int ml   = lane & 15;
  const int quad = lane >> 4;
  const int bn = blockIdx.x * 64, bm = blockIdx.y * 64;
  const int kStart = blockIdx.z * kChunk, kEnd = kStart + kChunk;

  f32x4 acc[4];
#pragma unroll
  for (int nt = 0; nt < 4; ++nt) acc[nt] = (f32x4){0.f, 0.f, 0.f, 0.f};

  const float* Arow = A + (size_t)(bm + r) * K + seg;
  const float* Wrow = W + (size_t)(bn + r) * K + seg;

  float4 a0 = *(const float4*)(Arow + kStart);
  float4 a1 = *(const float4*)(Arow + kStart + 4);
  float4 w0 = *(const float4*)(Wrow + kStart);
  float4 w1 = *(const float4*)(Wrow + kStart + 4);

  for (int k0 = kStart; k0 < kEnd; k0 += 32) {
    float av[8] = {a0.x, a0.y, a0.z, a0.w, a1.x, a1.y, a1.z, a1.w};
    float wq[8] = {w0.x, w0.y, w0.z, w0.w, w1.x, w1.y, w1.z, w1.w};
    s16x8 ah, al, wh, wl;
#pragma unroll
    for (int j = 0; j < 8; ++j) {
      short h = f2bf(av[j]);
      ah[j] = h; al[j] = f2bf(av[j] - bf2f(h));
      short g = f2bf(wq[j]);
      wh[j] = g; wl[j] = f2bf(wq[j] - bf2f(g));
    }
    __syncthreads();   // previous iteration's frag reads done
    *(s16x8*)&Ahi[r][seg] = ah;
    *(s16x8*)&Alo[r][seg] = al;
    *(s16x8*)&Whi[r][seg] = wh;
    *(s16x8*)&Wlo[r][seg] = wl;
    __syncthreads();
    if (k0 + 32 < kEnd) {                    // prefetch next K-tile
      a0 = *(const float4*)(Arow + k0 + 32);
      a1 = *(const float4*)(Arow + k0 + 36);
      w0 = *(const float4*)(Wrow + k0 + 32);
      w1 = *(const float4*)(Wrow + k0 + 36);
    }
    s16x8 fah = *(const s16x8*)&Ahi[wv * 16 + ml][quad * 8];
    s16x8 fal = *(const s16x8*)&Alo[wv * 16 + ml][quad * 8];
#pragma unroll
    for (int nt = 0; nt < 4; ++nt) {
      s16x8 fwh = *(const s16x8*)&Whi[nt * 16 + ml][quad * 8];
      s16x8 fwl = *(const s16x8*)&Wlo[nt * 16 + ml][quad * 8];
      acc[nt] = __builtin_amdgcn_mfma_f32_16x16x32_bf16(fah, fwh, acc[nt], 0, 0, 0);
      acc[nt] = __builtin_amdgcn_mfma_f32_16x16x32_bf16(fah, fwl, acc[nt], 0, 0, 0);
      acc[nt] = __builtin_amdgcn_mfma_f32_16x16x32_bf16(fal, fwh, acc[nt], 0, 0, 0);
    }
  }

  // C/D layout: col = lane&15 (n), row = quad*4 + reg (within wave's 16 rows)
  if (gridDim.z > 1) {
    float* P = Cout + (size_t)blockIdx.z * M * N;
#pragma unroll
    for (int nt = 0; nt < 4; ++nt) {
      int n = bn + nt * 16 + ml;
#pragma unroll
      for (int i = 0; i < 4; ++i) {
        int m = bm + wv * 16 + quad * 4 + i;
        P[(size_t)m * N + n] = acc[nt][i];
      }
    }
  } else {
#pragma unroll
    for (int nt = 0; nt < 4; ++nt) {
      int n = bn + nt * 16 + ml;
      float bv = bias ? bias[n] : 0.0f;
#pragma unroll
      for (int i = 0; i < 4; ++i) {
        int m = bm + wv * 16 + quad * 4 + i;
        float v = acc[nt][i] + bv;
        if (act) v = v > 0.0f ? v : 0.0f;
        Cout[(size_t)m * N + n] = v;
      }
    }
  }
}

// ---------------------------------------------------------------------------
// split-K reduce + bias + relu (enc1).  N must be pow2 (2048).
// ---------------------------------------------------------------------------
__global__ __launch_bounds__(256) void reduce_k(const float* __restrict__ P,
                                                const float* __restrict__ bias,
                                                float* __restrict__ Out,
                                                int MN, int N, int S) {
  int i = blockIdx.x * 256 + threadIdx.x;
  if (i >= MN) return;
  float s = 0.0f;
  for (int z = 0; z < S; ++z) s += P[(size_t)z * MN + i];
  s += bias[i & (N - 1)];
  Out[i] = s > 0.0f ? s : 0.0f;
}

// ---------------------------------------------------------------------------
// weight preps: conv_w (C,E,5) -> wT[(e*5+t)*C + c]; x_proj_w (48,512) -> padded (64,512)
// ---------------------------------------------------------------------------
__global__ __launch_bounds__(256) void prep_convw_k(const float* __restrict__ cw,
                                                    float* __restrict__ wT) {
  int et = blockIdx.x;                 // 0..639 = e*5+t
  int c = threadIdx.x;                 // 0..255
  wT[et * 256 + c] = cw[c * 640 + et];
}

__global__ __launch_bounds__(256) void prep_xpw_k(const float* __restrict__ w,
                                                  float* __restrict__ wp) {
  int i = blockIdx.x * 256 + threadIdx.x;   // 0..32767
  int n = i >> 9, k = i & 511;
  wp[i] = (n < 48) ? w[n * 512 + k] : 0.0f;
}

// ---------------------------------------------------------------------------
// conv1d(k=5,pad=2) + bias + relu + maxpool2 -> xs (B, 128, 256)
// ---------------------------------------------------------------------------
__global__ __launch_bounds__(256) void conv_pool_k(const float* __restrict__ h2,
                                                   const float* __restrict__ wT,
                                                   const float* __restrict__ cb,
                                                   float* __restrict__ xs) {
  __shared__ float in[20][128];
  int b = blockIdx.x;
  int l0 = blockIdx.y * 16;
  for (int idx = threadIdx.x; idx < 20 * 128; idx += 256) {
    int r = idx >> 7, e = idx & 127;
    int l = l0 - 2 + r;
    in[r][e] = (l >= 0 && l < L_) ? h2[((size_t)b * L_ + l) * E_ + e] : 0.0f;
  }
  __syncthreads();
  int c = threadIdx.x;                 // output channel
  float acc[16];
  float bc = cb[c];
#pragma unroll
  for (int l = 0; l < 16; ++l) acc[l] = bc;
  for (int e = 0; e < 128; ++e) {
    float vin[20];
#pragma unroll
    for (int r = 0; r < 20; ++r) vin[r] = in[r][e];
#pragma unroll
    for (int t = 0; t < 5; ++t) {
      float w = wT[(e * 5 + t) * 256 + c];
#pragma unroll
      for (int l = 0; l < 16; ++l) acc[l] = fmaf(vin[l + t], w, acc[l]);
    }
  }
  int l2 = l0 >> 1;
#pragma unroll
  for (int p = 0; p < 8; ++p) {
    float v0 = acc[2 * p]     > 0.0f ? acc[2 * p]     : 0.0f;
    float v1 = acc[2 * p + 1] > 0.0f ? acc[2 * p + 1] : 0.0f;
    xs[((size_t)b * LP_ + l2 + p) * C_ + c] = v0 > v1 ? v0 : v1;
  }
}

// ---------------------------------------------------------------------------
// depthwise causal conv4 + SiLU on u = xz[:, :512] -> u2
// ---------------------------------------------------------------------------
__global__ __launch_bounds__(512) void dwconv_k(const float* __restrict__ xz,
                                               const float* __restrict__ cw,
                                               const float* __restrict__ cb,
                                               float* __restrict__ u2) {
  int m = blockIdx.x;                  // b*128 + t
  int t = m & (LP_ - 1);
  int d = threadIdx.x;
  float4 w = *(const float4*)(cw + d * 4);
  const float* base = xz + (size_t)m * (2 * DI_) + d;
  float pre = cb[d];
  if (t >= 3) {
    pre = fmaf(base[-3 * 2 * DI_], w.x, pre);
    pre = fmaf(base[-2 * 2 * DI_], w.y, pre);
    pre = fmaf(base[-1 * 2 * DI_], w.z, pre);
    pre = fmaf(base[0],            w.w, pre);
  } else {
    const float wv[4] = {w.x, w.y, w.z, w.w};
    for (int j = 0; j < 4; ++j) {
      int tt = t - 3 + j;
      if (tt >= 0) pre = fmaf(base[(j - 3) * 2 * DI_], wv[j], pre);
    }
  }
  float s = pre / (1.0f + __expf(-pre));  // silu
  u2[(size_t)m * DI_ + d] = s;
}

// ---------------------------------------------------------------------------
// delta = softplus(dt @ dt_proj_w.T + dt_proj_b); dt = xdbl[:, :16] (row stride 64)
// ---------------------------------------------------------------------------
__global__ __launch_bounds__(512) void delta_k(const float* __restrict__ xdbl,
                                               const float* __restrict__ dtw,
                                               const float* __restrict__ dtb,
                                               float* __restrict__ delta) {
  __shared__ float dt[16];
  int m = blockIdx.x;
  int d = threadIdx.x;
  if (d < 16) dt[d] = xdbl[(size_t)m * 64 + d];
  __syncthreads();
  float acc = dtb[d];
  const float* wr = dtw + d * 16;
#pragma unroll
  for (int r = 0; r < 16; ++r) acc = fmaf(dt[r], wr[r], acc);
  float sp = (acc > 0.0f ? acc : 0.0f) + log1pf(__expf(-fabsf(acc)));
  delta[(size_t)m * DI_ + d] = sp;
}

// ---------------------------------------------------------------------------
// selective scan + D skip + z gate -> yg (8192, 512)
// 16 lanes per (b,d) channel — one lane per state n; shfl_xor width-16 reduce.
// ---------------------------------------------------------------------------
__global__ __launch_bounds__(256) void scan_k(const float* __restrict__ delta,
                                              const float* __restrict__ u2,
                                              const float* __restrict__ xz,
                                              const float* __restrict__ xdbl,
                                              const float* __restrict__ A_log,
                                              const float* __restrict__ Dp,
                                              float* __restrict__ yg) {
  int tid = threadIdx.x;
  int n = tid & 15;                    // state index
  int ch = tid >> 4;                   // channel within block (0..15)
  int b = blockIdx.x >> 5;             // 32 blocks per batch row
  int d = ((blockIdx.x & 31) << 4) + ch;
  float An = -__expf(A_log[d * 16 + n]);
  float Dd = Dp[d];
  float h = 0.0f;
  const size_t mBase = (size_t)b * LP_;
  for (int t = 0; t < LP_; ++t) {
    size_t m = mBase + t;
    float dl = delta[m * DI_ + d];     // broadcast across 16 lanes
    float uu = u2[m * DI_ + d];
    float Bn = xdbl[m * 64 + 16 + n];
    float Cn = xdbl[m * 64 + 32 + n];
    float dA = __expf(dl * An);
    h = fmaf(dA, h, (dl * uu) * Bn);
    float y = h * Cn;
    y += __shfl_xor(y, 1, 16);
    y += __shfl_xor(y, 2, 16);
    y += __shfl_xor(y, 4, 16);
    y += __shfl_xor(y, 8, 16);
    if (n == 0) {
      float zz = xz[m * (2 * DI_) + DI_ + d];
      float g = zz / (1.0f + __expf(-zz));
      yg[m * DI_ + d] = fmaf(uu, Dd, y) * g;
    }
  }
}

// ---------------------------------------------------------------------------
// mean over t + fc head -> out (64, 10)
// ---------------------------------------------------------------------------
__global__ __launch_bounds__(256) void meanfc_k(const float* __restrict__ mout,
                                               const float* __restrict__ fcw,
                                               const float* __restrict__ fcb,
                                               float* __restrict__ out) {
  __shared__ float pooled[256];
  int b = blockIdx.x;
  int c = threadIdx.x;
  float s = 0.0f;
  for (int t = 0; t < LP_; ++t) s += mout[((size_t)b * LP_ + t) * C_ + c];
  pooled[c] = s * (1.0f / 128.0f);
  __syncthreads();
  if (c < 10) {
    float acc = fcb[c];
    for (int k = 0; k < 256; ++k) acc = fmaf(pooled[k], fcw[c * 256 + k], acc);
    out[b * 10 + c] = acc;
  }
}

// ---------------------------------------------------------------------------
extern "C" void kernel_launch(void* const* d_in, const int* in_sizes, int n_in,
                              void* d_out, int out_size, void* d_ws, size_t ws_size,
                              hipStream_t stream) {
  const int*   x         = (const int*)d_in[0];
  const float* embed     = (const float*)d_in[1];
  const float* enc_w1    = (const float*)d_in[2];
  const float* enc_b1    = (const float*)d_in[3];
  const float* enc_w2    = (const float*)d_in[4];
  const float* enc_b2    = (const float*)d_in[5];
  const float* conv_w    = (const float*)d_in[6];
  const float* conv_b    = (const float*)d_in[7];
  const float* in_proj_w = (const float*)d_in[8];
  const float* conv1d_w  = (const float*)d_in[9];
  const float* conv1d_b  = (const float*)d_in[10];
  const float* x_proj_w  = (const float*)d_in[11];
  const float* dt_proj_w = (const float*)d_in[12];
  const float* dt_proj_b = (const float*)d_in[13];
  const float* A_log     = (const float*)d_in[14];
  const float* Dp        = (const float*)d_in[15];
  const float* out_proj_w= (const float*)d_in[16];
  const float* fc_w      = (const float*)d_in[17];
  const float* fc_b      = (const float*)d_in[18];
  float* out = (float*)d_out;

  char* ws = (char*)d_ws;
  size_t off = 0;
  auto alloc = [&](size_t bytes) {
    char* p = ws + off;
    off += (bytes + 255) & ~(size_t)255;
    return p;
  };
  float*  e    = (float*) alloc(2097152ull * 4);  // (64, 32768)
  float*  P    = (float*) alloc(2097152ull * 4);  // split-K partials (16,64,2048)
  float*  h1   = (float*) alloc(131072ull  * 4);  // (64, 2048)
  float*  h2   = (float*) alloc(2097152ull * 4);  // (64, 32768)
  float*  wT   = (float*) alloc(163840ull  * 4);  // conv weights (e*5+t, c)
  float*  xs   = (float*) alloc(2097152ull * 4);  // (8192, 256)
  float*  xz   = (float*) alloc(8388608ull * 4);  // (8192, 1024)
  float*  u2   = (float*) alloc(4194304ull * 4);  // (8192, 512)
  float*  xpw  = (float*) alloc(32768ull   * 4);  // padded x_proj_w (64, 512)
  float*  xdbl = (float*) alloc(524288ull  * 4);  // (8192, 64)
  float*  dl   = (float*) alloc(4194304ull * 4);  // delta (8192, 512)
  float*  yg   = (float*) alloc(4194304ull * 4);  // gated y (8192, 512)
  float*  mout = (float*) alloc(2097152ull * 4);  // (8192, 256)
  (void)ws_size; (void)in_sizes; (void)n_in; (void)out_size;

  embed_k<<<16384, 64, 0, stream>>>(x, embed, e);
  prep_convw_k<<<640, 256, 0, stream>>>(conv_w, wT);
  prep_xpw_k<<<128, 256, 0, stream>>>(x_proj_w, xpw);

  // enc1: (64,2048,K=32768), split-K=16 -> 512 blocks
  gemm_mfma_k<<<dim3(32, 1, 16), 256, 0, stream>>>(e, enc_w1, nullptr, P,
                                                   64, 2048, 32768, 2048, 0);
  reduce_k<<<512, 256, 0, stream>>>(P, enc_b1, h1, 131072, 2048, 16);

  // enc2: (64,32768,K=2048), bias+relu fused -> 512 blocks
  gemm_mfma_k<<<dim3(512, 1, 1), 256, 0, stream>>>(h1, enc_w2, enc_b2, h2,
                                                   64, 32768, 2048, 2048, 1);

  conv_pool_k<<<dim3(64, 16), 256, 0, stream>>>(h2, wT, conv_b, xs);

  // in_proj: (8192,1024,K=256)
  gemm_mfma_k<<<dim3(16, 128, 1), 256, 0, stream>>>(xs, in_proj_w, nullptr, xz,
                                                    8192, 1024, 256, 256, 0);

  dwconv_k<<<8192, 512, 0, stream>>>(xz, conv1d_w, conv1d_b, u2);

  // x_proj (padded to N=64): (8192,64,K=512)
  gemm_mfma_k<<<dim3(1, 128, 1), 256, 0, stream>>>(u2, xpw, nullptr, xdbl,
                                                   8192, 64, 512, 512, 0);

  delta_k<<<8192, 512, 0, stream>>>(xdbl, dt_proj_w, dt_proj_b, dl);

  scan_k<<<2048, 256, 0, stream>>>(dl, u2, xz, xdbl, A_log, Dp, yg);

  // out_proj: (8192,256,K=512)
  gemm_mfma_k<<<dim3(4, 128, 1), 256, 0, stream>>>(yg, out_proj_w, nullptr, mout,
                                                   8192, 256, 512, 512, 0);

  meanfc_k<<<64, 256, 0, stream>>>(mout, fc_w, fc_b, out);
}